// Round 23
// baseline (204.679 us; speedup 1.0000x reference)
//
#include <hip/hip_runtime.h>

// ---------------------------------------------------------------------------
// GCN pipeline, round 23 (round-22 agg/place kernels verbatim; CSR-build
// chain consolidated via atomic reservation):
//   coarse_count (LDS hist -> global 512-bucket histogram) -> scan_coarse
//   (1 block: gbase + padded gcur) -> multisplit_a (per-tile LDS hist,
//   ONE atomicAdd per (tile,bucket) reservation on 128B-padded cursors,
//   counting sort, coalesced run copy) -> place_fine2 -> agg1_t12 ->
//   agg2_fc.
// Round-5's atomic multisplit was slow due to 196-block occupancy, not the
// atomics; at 782 blocks + line-padded cursors the reservation replaces
// scanTiles + histG/offsG round-trips. Bucket-internal edge order becomes
// nondeterministic (commutative fp32 sums - harmless).
// ---------------------------------------------------------------------------

#define MS_TILE 2048
#define MAXB 512  // padded coarse-bucket count (NBkt = ceil(n/256) <= 512)
#define AGG_NODES 32
#define AGG_STAGE 1024
#define CUR_PAD 32  // gcur stride in ints: one 128B line per cursor

typedef __attribute__((ext_vector_type(4))) _Float16 half4;
typedef __attribute__((ext_vector_type(8))) _Float16 half8;

// Inclusive shfl scan across the wave; then cross-wave combine via wsum[4].
__device__ inline int scan256_incl(int v, int lane, int w, int* wsum,
                                   int* total) {
    int incl = v;
#pragma unroll
    for (int d = 1; d < 64; d <<= 1) {
        int up = __shfl_up(incl, d, 64);
        if (lane >= d) incl += up;
    }
    if (lane == 63) wsum[w] = incl;
    __syncthreads();
    int add = 0;
    if (w > 0) add += wsum[0];
    if (w > 1) add += wsum[1];
    if (w > 2) add += wsum[2];
    *total = wsum[0] + wsum[1] + wsum[2] + wsum[3];
    return incl + add;
}

// per-tile LDS histogram of dst>>8 -> one global atomicAdd per bucket
__global__ __launch_bounds__(256) void coarse_count(const int* __restrict__ dst,
                                                    int* __restrict__ gcount,
                                                    int E) {
    __shared__ int h[MAXB];
    int t = threadIdx.x;
    h[t] = 0;
    h[t + 256] = 0;
    __syncthreads();
    int base = blockIdx.x * MS_TILE;
    int cnt = min(MS_TILE, E - base);
    for (int k = t; k < cnt; k += 256) atomicAdd(&h[dst[base + k] >> 8], 1);
    __syncthreads();
    if (h[t]) atomicAdd(&gcount[t], h[t]);
    if (h[t + 256]) atomicAdd(&gcount[t + 256], h[t + 256]);
}

// single block: exclusive scan of 512 bucket counts -> gbase; init padded gcur
__global__ __launch_bounds__(256) void scan_coarse(const int* __restrict__ gcount,
                                                   int* __restrict__ gbase,
                                                   int* __restrict__ gcurP, int E) {
    __shared__ int wsum[4];
    int t = threadIdx.x;
    int lane = t & 63, w = t >> 6;
    int a0 = gcount[2 * t], a1 = gcount[2 * t + 1];
    int s = a0 + a1;
    int tot;
    int incl = scan256_incl(s, lane, w, wsum, &tot);
    int ex = incl - s;
    gbase[2 * t] = ex;
    gbase[2 * t + 1] = ex + a0;
    gcurP[(2 * t) * CUR_PAD] = ex;
    gcurP[(2 * t + 1) * CUR_PAD] = ex + a0;
    if (t == 255) gbase[MAXB] = E;
}

// Tile counting-sort with atomic reservation. Payload: (src<<8)|(dst&255).
__global__ __launch_bounds__(256) void multisplit_a(
    const int* __restrict__ src, const int* __restrict__ dst,
    int* __restrict__ gcurP, unsigned* __restrict__ binned, int E) {
    __shared__ unsigned stage[MS_TILE];
    __shared__ unsigned short sb[MS_TILE];
    __shared__ int hist[MAXB];
    __shared__ int hoff[MAXB + 1];
    __shared__ int hcur[MAXB];
    __shared__ int gb[MAXB];
    __shared__ int wsum[4];
    int t = threadIdx.x;
    int lane = t & 63, w = t >> 6;
    int base = blockIdx.x * MS_TILE;
    int cnt = min(MS_TILE, E - base);

    hist[t] = 0;
    hist[t + 256] = 0;
    __syncthreads();
    for (int k = t; k < cnt; k += 256) atomicAdd(&hist[dst[base + k] >> 8], 1);
    __syncthreads();
    int a0 = hist[2 * t], a1 = hist[2 * t + 1];
    int s = a0 + a1;
    int tot;
    int incl = scan256_incl(s, lane, w, wsum, &tot);
    int ex = incl - s;
    hoff[2 * t] = ex;
    hoff[2 * t + 1] = ex + a0;
    hcur[2 * t] = ex;
    hcur[2 * t + 1] = ex + a0;
    if (t == 255) hoff[MAXB] = cnt;
    // reservation: one global atomic per nonempty bucket (line-padded cursor)
    if (a0) gb[2 * t] = atomicAdd(&gcurP[(2 * t) * CUR_PAD], a0);
    if (a1) gb[2 * t + 1] = atomicAdd(&gcurP[(2 * t + 1) * CUR_PAD], a1);
    __syncthreads();
    for (int k = t; k < cnt; k += 256) {
        int d = dst[base + k];
        int b = d >> 8;
        int p = atomicAdd(&hcur[b], 1);
        stage[p] = ((unsigned)src[base + k] << 8) | (unsigned)(d & 255);
        sb[p] = (unsigned short)b;
    }
    __syncthreads();
    for (int k = t; k < cnt; k += 256) {
        int b = sb[k];
        binned[gb[b] + (k - hoff[b])] = stage[k];
    }
}

// Per coarse bucket: per-node deg via LDS count, shfl scan -> offs, dinv,
// y[i,:] = dinv[i]*x[i,:] (8 fp16 = 16B rows), then exact CSR scatter.
__global__ __launch_bounds__(256) void place_fine2(
    const unsigned* __restrict__ binned, const int* __restrict__ gbase,
    const float* __restrict__ x, int* __restrict__ offs,
    float* __restrict__ dinv, _Float16* __restrict__ y, int* __restrict__ srcs,
    int n) {
    __shared__ int cnt[256];
    __shared__ int lcur[256];
    __shared__ int wsum[4];
    int t = threadIdx.x, b = blockIdx.x;
    int lane = t & 63, w = t >> 6;
    int node0 = b << 8;
    int nn = min(256, n - node0);
    int e0 = gbase[b], e1 = gbase[b + 1];
    cnt[t] = 0;
    __syncthreads();
    for (int k = e0 + t; k < e1; k += 256) atomicAdd(&cnt[binned[k] & 255u], 1);
    __syncthreads();
    int c = cnt[t];
    int tot;
    int incl = scan256_incl(c, lane, w, wsum, &tot);
    int myoff = e0 + (incl - c);
    lcur[t] = myoff;
    if (t < nn) {
        int node = node0 + t;
        offs[node] = myoff;
        float di = 1.0f / sqrtf((float)(c + 1));  // +1 self loop
        dinv[node] = di;
        const float* xr = x + (size_t)node * 5;
        half8 hv;
        hv[0] = (_Float16)(xr[0] * di);
        hv[1] = (_Float16)(xr[1] * di);
        hv[2] = (_Float16)(xr[2] * di);
        hv[3] = (_Float16)(xr[3] * di);
        hv[4] = (_Float16)(xr[4] * di);
        hv[5] = (_Float16)0.f;
        hv[6] = (_Float16)0.f;
        hv[7] = (_Float16)0.f;
        *(half8*)(y + (size_t)node * 8) = hv;
    }
    __syncthreads();
    for (int k = e0 + t; k < e1; k += 256) {
        unsigned wd = binned[k];
        int p = atomicAdd(&lcur[wd & 255u], 1);
        srcs[p] = (int)(wd >> 8);
    }
}

// FUSED layer-1 aggregate + both transforms, 32-node blocks (3125 blocks).
// Gather: 8 threads/node, ONE 16B half8 load per edge, fp32 accumulate,
// shfl-xor reduce; z in LDS. h2 written as fp16.
__global__ __launch_bounds__(256) void agg1_t12(
    const _Float16* __restrict__ y, const int* __restrict__ srcs,
    const int* __restrict__ offs, const float* __restrict__ dinv,
    const float* __restrict__ W1, const float* __restrict__ b1,
    const float* __restrict__ W2, _Float16* __restrict__ h2, int n, int E) {
    __shared__ float w1s[320];
    __shared__ float b1s[64];
    __shared__ float w2s[64 * 32];
    __shared__ float o1[32 * 64];
    __shared__ float zs[32 * 6];
    int t = threadIdx.x;
    w1s[t] = W1[t];
    if (t < 64) {
        w1s[t + 256] = W1[t + 256];
        b1s[t] = b1[t];
    }
#pragma unroll
    for (int r = 0; r < 8; ++r) w2s[r * 256 + t] = W2[r * 256 + t];

    int node0 = blockIdx.x * 32;
    int li = t >> 3, e = t & 7;
    int i = node0 + li;
    const half8* yv = (const half8*)y;
    float a0 = 0.f, a1 = 0.f, a2 = 0.f, a3 = 0.f, a4 = 0.f;
    if (i < n) {
        int off = offs[i];
        int cnt = ((i + 1 < n) ? offs[i + 1] : E) - off;
        if (e == 0) {  // self-loop term once per node
            half8 v = yv[i];
            a0 = (float)v[0]; a1 = (float)v[1]; a2 = (float)v[2];
            a3 = (float)v[3]; a4 = (float)v[4];
        }
        for (int p = e; p < cnt; p += 8) {
            half8 v = yv[srcs[off + p]];
            a0 += (float)v[0]; a1 += (float)v[1]; a2 += (float)v[2];
            a3 += (float)v[3]; a4 += (float)v[4];
        }
    }
#pragma unroll
    for (int m = 4; m >= 1; m >>= 1) {
        a0 += __shfl_xor(a0, m, 64);
        a1 += __shfl_xor(a1, m, 64);
        a2 += __shfl_xor(a2, m, 64);
        a3 += __shfl_xor(a3, m, 64);
        a4 += __shfl_xor(a4, m, 64);
    }
    if (i < n && e == 0) {
        float di = dinv[i];
        zs[li * 6 + 0] = a0 * di;
        zs[li * 6 + 1] = a1 * di;
        zs[li * 6 + 2] = a2 * di;
        zs[li * 6 + 3] = a3 * di;
        zs[li * 6 + 4] = a4 * di;
        zs[li * 6 + 5] = di;
    }
    __syncthreads();
#pragma unroll
    for (int r = 0; r < 8; ++r) {
        int idx = r * 256 + t;
        int lj = idx >> 6, f = idx & 63;
        if (node0 + lj < n) {
            const float* zr = zs + lj * 6;
            float acc = b1s[f];
#pragma unroll
            for (int k = 0; k < 5; ++k) acc += zr[k] * w1s[k * 64 + f];
            o1[lj * 64 + f] = fmaxf(acc, 0.0f);
        }
    }
    __syncthreads();
#pragma unroll
    for (int r = 0; r < 4; ++r) {
        int idx = r * 256 + t;
        int lj = idx >> 5, g = idx & 31;
        int i2 = node0 + lj;
        if (i2 < n) {
            float acc = 0.f;
#pragma unroll
            for (int k = 0; k < 64; ++k) acc += o1[lj * 64 + k] * w2s[k * 32 + g];
            h2[(size_t)i2 * 32 + g] = (_Float16)(acc * zs[lj * 6 + 5]);
        }
    }
}

// FUSED layer-2 aggregate + FC head. fp16 h2 rows (64B), 8 threads/node
// each gathering 8B (half4); fp32 accumulation; LDS-staged CSR indices.
__global__ __launch_bounds__(256) void agg2_fc(
    const _Float16* __restrict__ h, const int* __restrict__ srcs,
    const int* __restrict__ offs, const float* __restrict__ dinv,
    const float* __restrict__ b2, const float* __restrict__ fcW1,
    const float* __restrict__ fcb1, const float* __restrict__ fcW2,
    const float* __restrict__ fcb2, float* __restrict__ out, int n, int E) {
    __shared__ int sidx[AGG_STAGE];
    __shared__ float sm[AGG_NODES * 33];
    __shared__ float x3s[AGG_NODES * 16];
    __shared__ float w1s[512];
    __shared__ float w2s[32];
    __shared__ float b1s[16];
    __shared__ float b2s[2];
    __shared__ float bs2[32];
    int t = threadIdx.x;
    w1s[t] = fcW1[t];
    w1s[t + 256] = fcW1[t + 256];
    if (t < 32) { w2s[t] = fcW2[t]; bs2[t] = b2[t]; }
    if (t < 16) b1s[t] = fcb1[t];
    if (t < 2) b2s[t] = fcb2[t];

    int node0 = blockIdx.x * AGG_NODES;
    int li = t >> 3, fq = t & 7;
    int i = node0 + li;
    bool live = (i < n);
    const char* hb = (const char*)h;

    int e0 = offs[node0];
    int eEnd = (node0 + AGG_NODES < n) ? offs[node0 + AGG_NODES] : E;
    int myOff = 0, myCnt = 0;
    float4 acc = {0.f, 0.f, 0.f, 0.f};
    if (live) {
        myOff = offs[i];
        myCnt = ((i + 1 < n) ? offs[i + 1] : E) - myOff;
        half4 sv = *(const half4*)(hb + ((size_t)i << 6) + (fq << 3));
        acc.x = (float)sv.x; acc.y = (float)sv.y;
        acc.z = (float)sv.z; acc.w = (float)sv.w;
    }

    for (int cs = e0; cs < eEnd; cs += AGG_STAGE) {
        int ce = min(cs + AGG_STAGE, eEnd);
        for (int k = cs + t; k < ce; k += 256) sidx[k - cs] = srcs[k] << 6;
        __syncthreads();
        int ps = max(myOff, cs), pe = min(myOff + myCnt, ce);
        int p = ps;
        for (; p + 8 <= pe; p += 8) {
            int o[8];
#pragma unroll
            for (int u = 0; u < 8; ++u) o[u] = sidx[p + u - cs];
            half4 v[8];
#pragma unroll
            for (int u = 0; u < 8; ++u)
                v[u] = *(const half4*)(hb + o[u] + (fq << 3));
#pragma unroll
            for (int u = 0; u < 8; ++u) {
                acc.x += (float)v[u].x; acc.y += (float)v[u].y;
                acc.z += (float)v[u].z; acc.w += (float)v[u].w;
            }
        }
        for (; p + 4 <= pe; p += 4) {
            int o0 = sidx[p - cs], o1 = sidx[p + 1 - cs];
            int o2 = sidx[p + 2 - cs], o3 = sidx[p + 3 - cs];
            half4 v0 = *(const half4*)(hb + o0 + (fq << 3));
            half4 v1 = *(const half4*)(hb + o1 + (fq << 3));
            half4 v2 = *(const half4*)(hb + o2 + (fq << 3));
            half4 v3 = *(const half4*)(hb + o3 + (fq << 3));
            acc.x += (float)v0.x + (float)v1.x + (float)v2.x + (float)v3.x;
            acc.y += (float)v0.y + (float)v1.y + (float)v2.y + (float)v3.y;
            acc.z += (float)v0.z + (float)v1.z + (float)v2.z + (float)v3.z;
            acc.w += (float)v0.w + (float)v1.w + (float)v2.w + (float)v3.w;
        }
        for (; p < pe; ++p) {
            half4 v = *(const half4*)(hb + sidx[p - cs] + (fq << 3));
            acc.x += (float)v.x; acc.y += (float)v.y;
            acc.z += (float)v.z; acc.w += (float)v.w;
        }
        __syncthreads();
    }

    if (live) {
        float di = dinv[i];
        int f0 = fq << 2;
        sm[li * 33 + f0 + 0] = fmaxf(di * acc.x + bs2[f0 + 0], 0.f);
        sm[li * 33 + f0 + 1] = fmaxf(di * acc.y + bs2[f0 + 1], 0.f);
        sm[li * 33 + f0 + 2] = fmaxf(di * acc.z + bs2[f0 + 2], 0.f);
        sm[li * 33 + f0 + 3] = fmaxf(di * acc.w + bs2[f0 + 3], 0.f);
    }
    __syncthreads();
#pragma unroll
    for (int r = 0; r < 2; ++r) {
        int idx = r * 256 + t;
        int lj = idx >> 4, j = idx & 15;
        if (node0 + lj < n) {
            float a = b1s[j];
#pragma unroll
            for (int k = 0; k < 32; ++k) a += sm[lj * 33 + k] * w1s[k * 16 + j];
            x3s[lj * 16 + j] = fmaxf(a, 0.f);
        }
    }
    __syncthreads();
    if (t < 64) {
        int lj = t >> 1, o = t & 1;
        if (node0 + lj < n) {
            float a = b2s[o];
#pragma unroll
            for (int j = 0; j < 16; ++j) a += x3s[lj * 16 + j] * w2s[j * 2 + o];
            out[(size_t)(node0 + lj) * 2 + o] = a;
        }
    }
}

extern "C" void kernel_launch(void* const* d_in, const int* in_sizes, int n_in,
                              void* d_out, int out_size, void* d_ws, size_t ws_size,
                              hipStream_t stream) {
    const float* edge_attr = (const float*)d_in[0];
    const int* edge_index  = (const int*)d_in[1];
    const float* W1   = (const float*)d_in[2];
    const float* b1   = (const float*)d_in[3];
    const float* W2   = (const float*)d_in[4];
    const float* b2   = (const float*)d_in[5];
    const float* fcW1 = (const float*)d_in[6];
    const float* fcb1 = (const float*)d_in[7];
    const float* fcW2 = (const float*)d_in[8];
    const float* fcb2 = (const float*)d_in[9];
    float* out = (float*)d_out;

    int n = in_sizes[0] / 5;
    int E = in_sizes[1] / 2;
    int NBkt = (n + 255) >> 8;                 // 391 for n=100000 (<= MAXB)
    int nTiles = (E + MS_TILE - 1) / MS_TILE;  // 782
    const int* src = edge_index;
    const int* dst = edge_index + E;

    char* ws = (char*)d_ws;
    auto alloc = [&](size_t bytes) {
        char* p = ws;
        ws += (bytes + 255) & ~(size_t)255;
        return p;
    };
    int*      offs   = (int*)alloc((size_t)n * 4);
    float*    dinv   = (float*)alloc((size_t)n * 4);
    int*      gcount = (int*)alloc((size_t)MAXB * 4);
    int*      gbase  = (int*)alloc((size_t)(MAXB + 1) * 4);
    int*      gcurP  = (int*)alloc((size_t)MAXB * CUR_PAD * 4);
    int*      srcs   = (int*)alloc((size_t)E * 4);
    unsigned* binned = (unsigned*)alloc((size_t)E * 4);
    _Float16* y      = (_Float16*)alloc((size_t)n * 8 * 2);
    _Float16* h2     = (_Float16*)alloc((size_t)n * 32 * 2);

    hipMemsetAsync(gcount, 0, (size_t)MAXB * 4, stream);

    coarse_count<<<nTiles, 256, 0, stream>>>(dst, gcount, E);
    scan_coarse<<<1, 256, 0, stream>>>(gcount, gbase, gcurP, E);
    multisplit_a<<<nTiles, 256, 0, stream>>>(src, dst, gcurP, binned, E);
    place_fine2<<<NBkt, 256, 0, stream>>>(binned, gbase, edge_attr, offs, dinv,
                                          y, srcs, n);
    agg1_t12<<<(n + 31) / 32, 256, 0, stream>>>(y, srcs, offs, dinv, W1, b1, W2,
                                                h2, n, E);
    agg2_fc<<<(n + AGG_NODES - 1) / AGG_NODES, 256, 0, stream>>>(
        h2, srcs, offs, dinv, b2, fcW1, fcb1, fcW2, fcb2, out, n, E);
}

// Round 24
// 176.632 us; speedup vs baseline: 1.1588x; 1.1588x over previous
//
#include <hip/hip_runtime.h>

// ---------------------------------------------------------------------------
// GCN pipeline, round 24 (= round-22 verbatim, reverting round-23's atomic
// reservation):
//   histA -> scanTiles -> multisplit2 (deterministic counting sort + folded
//   bucket-base scan) -> place_fine2 (y in fp16, 16B rows) -> agg1_t12
//   (single 16B half8 load per edge, fp32 accumulate, fused W1/relu/W2,
//   h2 out fp16) -> agg2_fc (fp16 h2 gathers + FC head).
// Round-23 lesson: global atomic reservation (400K cross-XCD RMWs, ~780-
// deep chains per cursor) costs ~27us vs scanTiles' ~13us — deterministic
// precomputed offsets beat atomics on this 8-XCD part at any granularity
// tried (r5: 196 blk, r11: LDS float atomics, r23: padded reservation).
// ---------------------------------------------------------------------------

#define MS_TILE 2048
#define MAXB 512  // padded coarse-bucket count (NBkt = ceil(n/256) <= 512)
#define AGG_NODES 32
#define AGG_STAGE 1024

typedef __attribute__((ext_vector_type(4))) _Float16 half4;
typedef __attribute__((ext_vector_type(8))) _Float16 half8;

// Inclusive shfl scan across the wave; then cross-wave combine via wsum[4].
__device__ inline int scan256_incl(int v, int lane, int w, int* wsum,
                                   int* total) {
    int incl = v;
#pragma unroll
    for (int d = 1; d < 64; d <<= 1) {
        int up = __shfl_up(incl, d, 64);
        if (lane >= d) incl += up;
    }
    if (lane == 63) wsum[w] = incl;
    __syncthreads();
    int add = 0;
    if (w > 0) add += wsum[0];
    if (w > 1) add += wsum[1];
    if (w > 2) add += wsum[2];
    *total = wsum[0] + wsum[1] + wsum[2] + wsum[3];
    return incl + add;
}

// per-tile LDS histogram of dst>>8 -> histG[tile*512 + b] (coalesced rows)
__global__ __launch_bounds__(256) void histA(const int* __restrict__ dst,
                                             int* __restrict__ histG, int E) {
    __shared__ int h[MAXB];
    int t = threadIdx.x;
    h[t] = 0;
    h[t + 256] = 0;
    __syncthreads();
    int base = blockIdx.x * MS_TILE;
    int cnt = min(MS_TILE, E - base);
    for (int k = t; k < cnt; k += 256) atomicAdd(&h[dst[base + k] >> 8], 1);
    __syncthreads();
    histG[blockIdx.x * MAXB + t] = h[t];
    histG[blockIdx.x * MAXB + 256 + t] = h[t + 256];
}

// one block per bucket b: exclusive scan of histG[.][b] across tiles
__global__ __launch_bounds__(256) void scanTiles(const int* __restrict__ histG,
                                                 int* __restrict__ offsG,
                                                 int* __restrict__ bucketTotal,
                                                 int nTiles) {
    __shared__ int wsum[4];
    int b = blockIdx.x, t = threadIdx.x;
    int lane = t & 63, w = t >> 6;
    int run = 0;
    for (int base = 0; base < nTiles; base += 256) {
        int idx = base + t;
        int v = (idx < nTiles) ? histG[idx * MAXB + b] : 0;
        int total;
        int incl = scan256_incl(v, lane, w, wsum, &total);
        if (idx < nTiles) offsG[idx * MAXB + b] = incl - v + run;
        run += total;
        __syncthreads();
    }
    if (t == 0) bucketTotal[b] = run;
}

// Deterministic tile counting-sort. Payload: (src<<8)|(dst&255).
__global__ __launch_bounds__(256) void multisplit2(
    const int* __restrict__ src, const int* __restrict__ dst,
    const int* __restrict__ histG, const int* __restrict__ offsG,
    const int* __restrict__ btot, int* __restrict__ gbaseOut,
    unsigned* __restrict__ binned, int E) {
    __shared__ unsigned stage[MS_TILE];
    __shared__ unsigned short sb[MS_TILE];
    __shared__ int hoff[MAXB + 1];
    __shared__ int hcur[MAXB];
    __shared__ int gb[MAXB];
    __shared__ int wsum[4];
    int t = threadIdx.x;
    int lane = t & 63, w = t >> 6;
    int tile = blockIdx.x;
    int base = tile * MS_TILE;
    int cnt = min(MS_TILE, E - base);

    int b0 = btot[2 * t], b1v = btot[2 * t + 1];
    int s2 = b0 + b1v;
    int tot2;
    int incl2 = scan256_incl(s2, lane, w, wsum, &tot2);
    int ex2 = incl2 - s2;
    gb[2 * t] = ex2 + offsG[tile * MAXB + 2 * t];
    gb[2 * t + 1] = ex2 + b0 + offsG[tile * MAXB + 2 * t + 1];
    if (tile == 0) {
        gbaseOut[2 * t] = ex2;
        gbaseOut[2 * t + 1] = ex2 + b0;
        if (t == 255) gbaseOut[MAXB] = E;
    }
    __syncthreads();

    int a0 = histG[tile * MAXB + 2 * t];
    int a1 = histG[tile * MAXB + 2 * t + 1];
    int s = a0 + a1;
    int tot;
    int incl = scan256_incl(s, lane, w, wsum, &tot);
    int ex = incl - s;
    hoff[2 * t] = ex;
    hoff[2 * t + 1] = ex + a0;
    hcur[2 * t] = ex;
    hcur[2 * t + 1] = ex + a0;
    if (t == 255) hoff[MAXB] = cnt;
    __syncthreads();
    for (int k = t; k < cnt; k += 256) {
        int d = dst[base + k];
        int b = d >> 8;
        int p = atomicAdd(&hcur[b], 1);
        stage[p] = ((unsigned)src[base + k] << 8) | (unsigned)(d & 255);
        sb[p] = (unsigned short)b;
    }
    __syncthreads();
    for (int k = t; k < cnt; k += 256) {
        int b = sb[k];
        binned[gb[b] + (k - hoff[b])] = stage[k];
    }
}

// Per coarse bucket: per-node deg via LDS count, shfl scan -> offs, dinv,
// y[i,:] = dinv[i]*x[i,:] (8 fp16 = 16B rows), then exact CSR scatter.
__global__ __launch_bounds__(256) void place_fine2(
    const unsigned* __restrict__ binned, const int* __restrict__ gbase,
    const float* __restrict__ x, int* __restrict__ offs,
    float* __restrict__ dinv, _Float16* __restrict__ y, int* __restrict__ srcs,
    int n) {
    __shared__ int cnt[256];
    __shared__ int lcur[256];
    __shared__ int wsum[4];
    int t = threadIdx.x, b = blockIdx.x;
    int lane = t & 63, w = t >> 6;
    int node0 = b << 8;
    int nn = min(256, n - node0);
    int e0 = gbase[b], e1 = gbase[b + 1];
    cnt[t] = 0;
    __syncthreads();
    for (int k = e0 + t; k < e1; k += 256) atomicAdd(&cnt[binned[k] & 255u], 1);
    __syncthreads();
    int c = cnt[t];
    int tot;
    int incl = scan256_incl(c, lane, w, wsum, &tot);
    int myoff = e0 + (incl - c);
    lcur[t] = myoff;
    if (t < nn) {
        int node = node0 + t;
        offs[node] = myoff;
        float di = 1.0f / sqrtf((float)(c + 1));  // +1 self loop
        dinv[node] = di;
        const float* xr = x + (size_t)node * 5;
        half8 hv;
        hv[0] = (_Float16)(xr[0] * di);
        hv[1] = (_Float16)(xr[1] * di);
        hv[2] = (_Float16)(xr[2] * di);
        hv[3] = (_Float16)(xr[3] * di);
        hv[4] = (_Float16)(xr[4] * di);
        hv[5] = (_Float16)0.f;
        hv[6] = (_Float16)0.f;
        hv[7] = (_Float16)0.f;
        *(half8*)(y + (size_t)node * 8) = hv;
    }
    __syncthreads();
    for (int k = e0 + t; k < e1; k += 256) {
        unsigned wd = binned[k];
        int p = atomicAdd(&lcur[wd & 255u], 1);
        srcs[p] = (int)(wd >> 8);
    }
}

// FUSED layer-1 aggregate + both transforms, 32-node blocks (3125 blocks).
// Gather: 8 threads/node, ONE 16B half8 load per edge, fp32 accumulate,
// shfl-xor reduce; z in LDS. h2 written as fp16.
__global__ __launch_bounds__(256) void agg1_t12(
    const _Float16* __restrict__ y, const int* __restrict__ srcs,
    const int* __restrict__ offs, const float* __restrict__ dinv,
    const float* __restrict__ W1, const float* __restrict__ b1,
    const float* __restrict__ W2, _Float16* __restrict__ h2, int n, int E) {
    __shared__ float w1s[320];
    __shared__ float b1s[64];
    __shared__ float w2s[64 * 32];
    __shared__ float o1[32 * 64];
    __shared__ float zs[32 * 6];
    int t = threadIdx.x;
    w1s[t] = W1[t];
    if (t < 64) {
        w1s[t + 256] = W1[t + 256];
        b1s[t] = b1[t];
    }
#pragma unroll
    for (int r = 0; r < 8; ++r) w2s[r * 256 + t] = W2[r * 256 + t];

    int node0 = blockIdx.x * 32;
    int li = t >> 3, e = t & 7;
    int i = node0 + li;
    const half8* yv = (const half8*)y;
    float a0 = 0.f, a1 = 0.f, a2 = 0.f, a3 = 0.f, a4 = 0.f;
    if (i < n) {
        int off = offs[i];
        int cnt = ((i + 1 < n) ? offs[i + 1] : E) - off;
        if (e == 0) {  // self-loop term once per node
            half8 v = yv[i];
            a0 = (float)v[0]; a1 = (float)v[1]; a2 = (float)v[2];
            a3 = (float)v[3]; a4 = (float)v[4];
        }
        for (int p = e; p < cnt; p += 8) {
            half8 v = yv[srcs[off + p]];
            a0 += (float)v[0]; a1 += (float)v[1]; a2 += (float)v[2];
            a3 += (float)v[3]; a4 += (float)v[4];
        }
    }
#pragma unroll
    for (int m = 4; m >= 1; m >>= 1) {
        a0 += __shfl_xor(a0, m, 64);
        a1 += __shfl_xor(a1, m, 64);
        a2 += __shfl_xor(a2, m, 64);
        a3 += __shfl_xor(a3, m, 64);
        a4 += __shfl_xor(a4, m, 64);
    }
    if (i < n && e == 0) {
        float di = dinv[i];
        zs[li * 6 + 0] = a0 * di;
        zs[li * 6 + 1] = a1 * di;
        zs[li * 6 + 2] = a2 * di;
        zs[li * 6 + 3] = a3 * di;
        zs[li * 6 + 4] = a4 * di;
        zs[li * 6 + 5] = di;
    }
    __syncthreads();
#pragma unroll
    for (int r = 0; r < 8; ++r) {
        int idx = r * 256 + t;
        int lj = idx >> 6, f = idx & 63;
        if (node0 + lj < n) {
            const float* zr = zs + lj * 6;
            float acc = b1s[f];
#pragma unroll
            for (int k = 0; k < 5; ++k) acc += zr[k] * w1s[k * 64 + f];
            o1[lj * 64 + f] = fmaxf(acc, 0.0f);
        }
    }
    __syncthreads();
#pragma unroll
    for (int r = 0; r < 4; ++r) {
        int idx = r * 256 + t;
        int lj = idx >> 5, g = idx & 31;
        int i2 = node0 + lj;
        if (i2 < n) {
            float acc = 0.f;
#pragma unroll
            for (int k = 0; k < 64; ++k) acc += o1[lj * 64 + k] * w2s[k * 32 + g];
            h2[(size_t)i2 * 32 + g] = (_Float16)(acc * zs[lj * 6 + 5]);
        }
    }
}

// FUSED layer-2 aggregate + FC head. fp16 h2 rows (64B), 8 threads/node
// each gathering 8B (half4); fp32 accumulation; LDS-staged CSR indices.
__global__ __launch_bounds__(256) void agg2_fc(
    const _Float16* __restrict__ h, const int* __restrict__ srcs,
    const int* __restrict__ offs, const float* __restrict__ dinv,
    const float* __restrict__ b2, const float* __restrict__ fcW1,
    const float* __restrict__ fcb1, const float* __restrict__ fcW2,
    const float* __restrict__ fcb2, float* __restrict__ out, int n, int E) {
    __shared__ int sidx[AGG_STAGE];
    __shared__ float sm[AGG_NODES * 33];
    __shared__ float x3s[AGG_NODES * 16];
    __shared__ float w1s[512];
    __shared__ float w2s[32];
    __shared__ float b1s[16];
    __shared__ float b2s[2];
    __shared__ float bs2[32];
    int t = threadIdx.x;
    w1s[t] = fcW1[t];
    w1s[t + 256] = fcW1[t + 256];
    if (t < 32) { w2s[t] = fcW2[t]; bs2[t] = b2[t]; }
    if (t < 16) b1s[t] = fcb1[t];
    if (t < 2) b2s[t] = fcb2[t];

    int node0 = blockIdx.x * AGG_NODES;
    int li = t >> 3, fq = t & 7;
    int i = node0 + li;
    bool live = (i < n);
    const char* hb = (const char*)h;

    int e0 = offs[node0];
    int eEnd = (node0 + AGG_NODES < n) ? offs[node0 + AGG_NODES] : E;
    int myOff = 0, myCnt = 0;
    float4 acc = {0.f, 0.f, 0.f, 0.f};
    if (live) {
        myOff = offs[i];
        myCnt = ((i + 1 < n) ? offs[i + 1] : E) - myOff;
        half4 sv = *(const half4*)(hb + ((size_t)i << 6) + (fq << 3));
        acc.x = (float)sv.x; acc.y = (float)sv.y;
        acc.z = (float)sv.z; acc.w = (float)sv.w;
    }

    for (int cs = e0; cs < eEnd; cs += AGG_STAGE) {
        int ce = min(cs + AGG_STAGE, eEnd);
        for (int k = cs + t; k < ce; k += 256) sidx[k - cs] = srcs[k] << 6;
        __syncthreads();
        int ps = max(myOff, cs), pe = min(myOff + myCnt, ce);
        int p = ps;
        for (; p + 8 <= pe; p += 8) {
            int o[8];
#pragma unroll
            for (int u = 0; u < 8; ++u) o[u] = sidx[p + u - cs];
            half4 v[8];
#pragma unroll
            for (int u = 0; u < 8; ++u)
                v[u] = *(const half4*)(hb + o[u] + (fq << 3));
#pragma unroll
            for (int u = 0; u < 8; ++u) {
                acc.x += (float)v[u].x; acc.y += (float)v[u].y;
                acc.z += (float)v[u].z; acc.w += (float)v[u].w;
            }
        }
        for (; p + 4 <= pe; p += 4) {
            int o0 = sidx[p - cs], o1 = sidx[p + 1 - cs];
            int o2 = sidx[p + 2 - cs], o3 = sidx[p + 3 - cs];
            half4 v0 = *(const half4*)(hb + o0 + (fq << 3));
            half4 v1 = *(const half4*)(hb + o1 + (fq << 3));
            half4 v2 = *(const half4*)(hb + o2 + (fq << 3));
            half4 v3 = *(const half4*)(hb + o3 + (fq << 3));
            acc.x += (float)v0.x + (float)v1.x + (float)v2.x + (float)v3.x;
            acc.y += (float)v0.y + (float)v1.y + (float)v2.y + (float)v3.y;
            acc.z += (float)v0.z + (float)v1.z + (float)v2.z + (float)v3.z;
            acc.w += (float)v0.w + (float)v1.w + (float)v2.w + (float)v3.w;
        }
        for (; p < pe; ++p) {
            half4 v = *(const half4*)(hb + sidx[p - cs] + (fq << 3));
            acc.x += (float)v.x; acc.y += (float)v.y;
            acc.z += (float)v.z; acc.w += (float)v.w;
        }
        __syncthreads();
    }

    if (live) {
        float di = dinv[i];
        int f0 = fq << 2;
        sm[li * 33 + f0 + 0] = fmaxf(di * acc.x + bs2[f0 + 0], 0.f);
        sm[li * 33 + f0 + 1] = fmaxf(di * acc.y + bs2[f0 + 1], 0.f);
        sm[li * 33 + f0 + 2] = fmaxf(di * acc.z + bs2[f0 + 2], 0.f);
        sm[li * 33 + f0 + 3] = fmaxf(di * acc.w + bs2[f0 + 3], 0.f);
    }
    __syncthreads();
#pragma unroll
    for (int r = 0; r < 2; ++r) {
        int idx = r * 256 + t;
        int lj = idx >> 4, j = idx & 15;
        if (node0 + lj < n) {
            float a = b1s[j];
#pragma unroll
            for (int k = 0; k < 32; ++k) a += sm[lj * 33 + k] * w1s[k * 16 + j];
            x3s[lj * 16 + j] = fmaxf(a, 0.f);
        }
    }
    __syncthreads();
    if (t < 64) {
        int lj = t >> 1, o = t & 1;
        if (node0 + lj < n) {
            float a = b2s[o];
#pragma unroll
            for (int j = 0; j < 16; ++j) a += x3s[lj * 16 + j] * w2s[j * 2 + o];
            out[(size_t)(node0 + lj) * 2 + o] = a;
        }
    }
}

extern "C" void kernel_launch(void* const* d_in, const int* in_sizes, int n_in,
                              void* d_out, int out_size, void* d_ws, size_t ws_size,
                              hipStream_t stream) {
    const float* edge_attr = (const float*)d_in[0];
    const int* edge_index  = (const int*)d_in[1];
    const float* W1   = (const float*)d_in[2];
    const float* b1   = (const float*)d_in[3];
    const float* W2   = (const float*)d_in[4];
    const float* b2   = (const float*)d_in[5];
    const float* fcW1 = (const float*)d_in[6];
    const float* fcb1 = (const float*)d_in[7];
    const float* fcW2 = (const float*)d_in[8];
    const float* fcb2 = (const float*)d_in[9];
    float* out = (float*)d_out;

    int n = in_sizes[0] / 5;
    int E = in_sizes[1] / 2;
    int NBkt = (n + 255) >> 8;                 // 391 for n=100000 (<= MAXB)
    int nTiles = (E + MS_TILE - 1) / MS_TILE;  // 782
    const int* src = edge_index;
    const int* dst = edge_index + E;

    char* ws = (char*)d_ws;
    auto alloc = [&](size_t bytes) {
        char* p = ws;
        ws += (bytes + 255) & ~(size_t)255;
        return p;
    };
    int*      offs   = (int*)alloc((size_t)n * 4);
    float*    dinv   = (float*)alloc((size_t)n * 4);
    int*      histG  = (int*)alloc((size_t)nTiles * MAXB * 4);
    int*      offsG  = (int*)alloc((size_t)nTiles * MAXB * 4);
    int*      btot   = (int*)alloc((size_t)MAXB * 4);
    int*      gbase  = (int*)alloc((size_t)(MAXB + 1) * 4);
    int*      srcs   = (int*)alloc((size_t)E * 4);
    unsigned* binned = (unsigned*)alloc((size_t)E * 4);
    _Float16* y      = (_Float16*)alloc((size_t)n * 8 * 2);
    _Float16* h2     = (_Float16*)alloc((size_t)n * 32 * 2);

    histA<<<nTiles, 256, 0, stream>>>(dst, histG, E);
    scanTiles<<<MAXB, 256, 0, stream>>>(histG, offsG, btot, nTiles);
    multisplit2<<<nTiles, 256, 0, stream>>>(src, dst, histG, offsG, btot, gbase,
                                            binned, E);
    place_fine2<<<NBkt, 256, 0, stream>>>(binned, gbase, edge_attr, offs, dinv,
                                          y, srcs, n);
    agg1_t12<<<(n + 31) / 32, 256, 0, stream>>>(y, srcs, offs, dinv, W1, b1, W2,
                                                h2, n, E);
    agg2_fc<<<(n + AGG_NODES - 1) / AGG_NODES, 256, 0, stream>>>(
        h2, srcs, offs, dinv, b2, fcW1, fcb1, fcW2, fcb2, out, n, E);
}